// Round 1
// baseline (1451.826 us; speedup 1.0000x reference)
//
#include <hip/hip_runtime.h>
#include <hip/hip_bf16.h>

#define NN 50000
#define NE 800000
#define FF 64
#define KC3 192
#define EPS 1e-5f

// ws layout (floats): stats block, 4KB total
// S_e 0, Q_e 64, S_m 128, Q_m 192, S_s 256, Q_s 320, S_n 384, Q_n 448,
// A_e 512, C_e 576, A_m 640, C_m 704, A_s 768, C_s 832, A_n 896, C_n 960
// optional: xbuf bf16 [E*64] at +4096; ybuf bf16 [E*128] after xbuf.
// agg lives in d_out (exactly N*64 floats), finalized in place.

__device__ __forceinline__ float silu_f(float x) {
    return x / (1.0f + __expf(-x));
}
__device__ __forceinline__ float softplus_f(float x) {
    return fmaxf(x, 0.0f) + log1pf(__expf(-fabsf(x)));
}

// ---------------- Phase 1: x_e = ef @ W_e + b_e ; column stats ----------------
template<bool STORE_X>
__global__ __launch_bounds__(256) void k_xe(
    const float* __restrict__ ef, const float* __restrict__ We,
    const float* __restrict__ bbias, float* __restrict__ st,
    __hip_bfloat16* __restrict__ xbuf)
{
    __shared__ float sWT[64][68];   // W_e transposed: sWT[j][k]
    __shared__ float sE[64][68];    // 64-edge tile of edge_feats
    __shared__ float sred[2][4][64];
    const int tx = threadIdx.x;
    const long e0 = (long)blockIdx.x * 64;

    for (int i = tx; i < 4096; i += 256) sWT[i & 63][i >> 6] = We[i];
    for (int i = tx; i < 4096; i += 256) sE[i >> 6][i & 63] = ef[e0 * 64 + i];
    __syncthreads();

    const int j = tx & 63, g = tx >> 6;
    const float bj = bbias[j];
    float ls = 0.f, lq = 0.f;
    for (int eb = 0; eb < 4; ++eb) {
        const int eb0 = g * 16 + eb * 4;
        float a0 = bj, a1 = bj, a2 = bj, a3 = bj;
        #pragma unroll
        for (int k = 0; k < 64; k += 4) {
            float4 wv = *(const float4*)&sWT[j][k];
            float4 v0 = *(const float4*)&sE[eb0 + 0][k];
            float4 v1 = *(const float4*)&sE[eb0 + 1][k];
            float4 v2 = *(const float4*)&sE[eb0 + 2][k];
            float4 v3 = *(const float4*)&sE[eb0 + 3][k];
            a0 += v0.x*wv.x + v0.y*wv.y + v0.z*wv.z + v0.w*wv.w;
            a1 += v1.x*wv.x + v1.y*wv.y + v1.z*wv.z + v1.w*wv.w;
            a2 += v2.x*wv.x + v2.y*wv.y + v2.z*wv.z + v2.w*wv.w;
            a3 += v3.x*wv.x + v3.y*wv.y + v3.z*wv.z + v3.w*wv.w;
        }
        ls += a0 + a1 + a2 + a3;
        lq += a0*a0 + a1*a1 + a2*a2 + a3*a3;
        if constexpr (STORE_X) {
            xbuf[(e0 + eb0 + 0) * 64 + j] = __float2bfloat16(a0);
            xbuf[(e0 + eb0 + 1) * 64 + j] = __float2bfloat16(a1);
            xbuf[(e0 + eb0 + 2) * 64 + j] = __float2bfloat16(a2);
            xbuf[(e0 + eb0 + 3) * 64 + j] = __float2bfloat16(a3);
        }
    }
    sred[0][g][j] = ls; sred[1][g][j] = lq;
    __syncthreads();
    if (tx < 64) {
        float s = sred[0][0][tx] + sred[0][1][tx] + sred[0][2][tx] + sred[0][3][tx];
        atomicAdd(&st[tx], s);
    } else if (tx < 128) {
        int jj = tx - 64;
        float q = sred[1][0][jj] + sred[1][1][jj] + sred[1][2][jj] + sred[1][3][jj];
        atomicAdd(&st[64 + jj], q);
    }
}

// ---------------- BN finalize: A = g*rsqrt(var+eps), C = beta - mean*A --------
__global__ void k_fin(const float* __restrict__ S, const float* __restrict__ Q,
                      const float* __restrict__ g, const float* __restrict__ b,
                      float inv_cnt, float* __restrict__ A, float* __restrict__ C)
{
    int j = threadIdx.x;
    float m = S[j] * inv_cnt;
    float v = Q[j] * inv_cnt - m * m;
    float a = g[j] * rsqrtf(v + EPS);
    A[j] = a;
    C[j] = b[j] - m * a;
}

// ---------------- Phase 2/3 core: y = h_combine @ [W_m|W_s] ------------------
// MODE 0: accumulate column stats (optionally store y bf16)
// MODE 1: msg = silu(bn_m(y_m)) * softplus(bn_s(y_s)); atomic scatter to agg
template<bool LOAD_X, int MODE, bool STORE_Y>
__global__ __launch_bounds__(256) void k_y(
    const float* __restrict__ nf, const float* __restrict__ ef,
    const int* __restrict__ src, const int* __restrict__ dst,
    const float* __restrict__ We, const float* __restrict__ be_bias,
    const float* __restrict__ Wm, const float* __restrict__ bm,
    const float* __restrict__ Ws, const float* __restrict__ bs,
    float* __restrict__ st, const __hip_bfloat16* __restrict__ xbuf,
    __hip_bfloat16* __restrict__ ybuf, float* __restrict__ agg)
{
    __shared__ float sHC[32][200];                 // h_combine tile [32 edges][192]
    __shared__ int   sIdx[64];                     // src 0..31, dst 32..63
    __shared__ float sred[2][2][128];
    __shared__ float sWT[LOAD_X ? 1 : 64][68];
    __shared__ float sE2[LOAD_X ? 1 : 32][68];

    const int tx = threadIdx.x;
    const long e0 = (long)blockIdx.x * 32;

    if (tx < 32) sIdx[tx] = src[e0 + tx];
    else if (tx < 64) sIdx[tx] = dst[e0 + tx - 32];
    if constexpr (!LOAD_X) {
        for (int i = tx; i < 4096; i += 256) sWT[i & 63][i >> 6] = We[i];
        for (int i = tx; i < 2048; i += 256) sE2[i >> 6][i & 63] = ef[e0 * 64 + i];
    }
    __syncthreads();

    // gather node rows into cols 0..127
    for (int i = tx; i < 32 * 128; i += 256) {
        int e = i >> 7, c = i & 127;
        int node = sIdx[(c < 64 ? 0 : 32) + e];
        sHC[e][c] = nf[(size_t)node * 64 + (c & 63)];
    }
    // hm into cols 128..191
    if constexpr (LOAD_X) {
        for (int i = tx; i < 32 * 64; i += 256) {
            int e = i >> 6, j = i & 63;
            float x = __bfloat162float(xbuf[(e0 + e) * 64 + j]);
            sHC[e][128 + j] = silu_f(fmaf(x, st[512 + j], st[576 + j]));
        }
    } else {
        const int j = tx & 63, g = tx >> 6;
        const float a = st[512 + j], c2 = st[576 + j], bj = be_bias[j];
        for (int ei = 0; ei < 8; ++ei) {
            int e = g + 4 * ei;
            float acc = bj;
            #pragma unroll
            for (int k = 0; k < 64; k += 4) {
                float4 ev = *(const float4*)&sE2[e][k];
                float4 wv = *(const float4*)&sWT[j][k];
                acc += ev.x*wv.x + ev.y*wv.y + ev.z*wv.z + ev.w*wv.w;
            }
            sHC[e][128 + j] = silu_f(fmaf(acc, a, c2));
        }
    }
    __syncthreads();

    // y = hc @ W (128 output cols: 0..63 -> W_m, 64..127 -> W_s)
    const int jj = tx & 127, g2 = tx >> 7;
    const bool is_m = jj < 64;
    const int jc = jj & 63;
    const float* W = is_m ? Wm : Ws;
    float acc[16];
    {
        float b = is_m ? bm[jc] : bs[jc];
        #pragma unroll
        for (int i = 0; i < 16; ++i) acc[i] = b;
    }
    for (int kc = 0; kc < KC3; kc += 8) {
        float w[8];
        #pragma unroll
        for (int t = 0; t < 8; ++t) w[t] = W[(kc + t) * 64 + jc];
        #pragma unroll
        for (int i = 0; i < 16; ++i) {
            int e = g2 + 2 * i;
            float4 h0 = *(const float4*)&sHC[e][kc];
            float4 h1 = *(const float4*)&sHC[e][kc + 4];
            acc[i] += h0.x*w[0] + h0.y*w[1] + h0.z*w[2] + h0.w*w[3]
                    + h1.x*w[4] + h1.y*w[5] + h1.z*w[6] + h1.w*w[7];
        }
    }

    if constexpr (MODE == 0) {
        float ls = 0.f, lq = 0.f;
        #pragma unroll
        for (int i = 0; i < 16; ++i) { ls += acc[i]; lq += acc[i] * acc[i]; }
        if constexpr (STORE_Y) {
            #pragma unroll
            for (int i = 0; i < 16; ++i)
                ybuf[(e0 + g2 + 2 * i) * 128 + jj] = __float2bfloat16(acc[i]);
        }
        sred[0][g2][jj] = ls; sred[1][g2][jj] = lq;
        __syncthreads();
        if (tx < 128) {
            float s = sred[0][0][tx] + sred[0][1][tx];
            float q = sred[1][0][tx] + sred[1][1][tx];
            if (tx < 64) { atomicAdd(&st[128 + tx], s); atomicAdd(&st[192 + tx], q); }
            else         { atomicAdd(&st[256 + tx - 64], s); atomicAdd(&st[320 + tx - 64], q); }
        }
    } else {
        __syncthreads();   // all k-loop reads of hm region done
        if (!is_m) {
            const float a = st[768 + jc], c2 = st[832 + jc];
            #pragma unroll
            for (int i = 0; i < 16; ++i) {
                int e = g2 + 2 * i;
                sHC[e][128 + jc] = softplus_f(fmaf(acc[i], a, c2));
            }
        }
        __syncthreads();
        if (is_m) {
            const float a = st[640 + jc], c2 = st[704 + jc];
            #pragma unroll
            for (int i = 0; i < 16; ++i) {
                int e = g2 + 2 * i;
                float m = silu_f(fmaf(acc[i], a, c2)) * sHC[e][128 + jc];
                atomicAdd(&agg[(size_t)sIdx[32 + e] * 64 + jc], m);
            }
        }
    }
}

// ---------------- Phase 3 (cached-y variant): msg + scatter -------------------
__global__ __launch_bounds__(256) void k_msg_load(
    const __hip_bfloat16* __restrict__ ybuf, const int* __restrict__ dst,
    const float* __restrict__ st, float* __restrict__ agg)
{
    const long total = (long)NE * 64;
    for (long t = (long)blockIdx.x * 256 + threadIdx.x; t < total;
         t += (long)gridDim.x * 256) {
        long e = t >> 6; int j = (int)(t & 63);
        float ym = __bfloat162float(ybuf[e * 128 + j]);
        float ys = __bfloat162float(ybuf[e * 128 + 64 + j]);
        float m = silu_f(fmaf(ym, st[640 + j], st[704 + j]))
                * softplus_f(fmaf(ys, st[768 + j], st[832 + j]));
        atomicAdd(&agg[(size_t)dst[e] * 64 + j], m);
    }
}

// ---------------- Phase 4: agg column stats ----------------------------------
__global__ __launch_bounds__(256) void k_aggstats(const float* __restrict__ agg,
                                                  float* __restrict__ st)
{
    __shared__ float red[2][4][64];
    float ls = 0.f, lq = 0.f;
    const long total = (long)NN * 64;
    for (long t = (long)blockIdx.x * 256 + threadIdx.x; t < total;
         t += (long)gridDim.x * 256) {
        float a = agg[t];
        ls += a; lq += a * a;
    }
    int j = threadIdx.x & 63, g = threadIdx.x >> 6;
    red[0][g][j] = ls; red[1][g][j] = lq;
    __syncthreads();
    if (threadIdx.x < 64) {
        float s = red[0][0][j] + red[0][1][j] + red[0][2][j] + red[0][3][j];
        atomicAdd(&st[384 + j], s);
    } else if (threadIdx.x < 128) {
        int jj = threadIdx.x - 64;
        float q = red[1][0][jj] + red[1][1][jj] + red[1][2][jj] + red[1][3][jj];
        atomicAdd(&st[448 + jj], q);
    }
}

// ---------------- Phase 5: out = softplus(bn_n(agg) + node_feats), in place ---
__global__ __launch_bounds__(256) void k_out(float* __restrict__ outagg,
                                             const float* __restrict__ nf,
                                             const float* __restrict__ st)
{
    long t = (long)blockIdx.x * 256 + threadIdx.x;
    int j = (int)(t & 63);
    float a = outagg[t];
    outagg[t] = softplus_f(fmaf(a, st[896 + j], st[960 + j]) + nf[t]);
}

extern "C" void kernel_launch(void* const* d_in, const int* in_sizes, int n_in,
                              void* d_out, int out_size, void* d_ws, size_t ws_size,
                              hipStream_t stream)
{
    (void)in_sizes; (void)n_in; (void)out_size;
    const float* nf  = (const float*)d_in[0];
    const float* ef  = (const float*)d_in[1];
    const int*   src = (const int*)d_in[2];
    const int*   dst = (const int*)d_in[3];
    const float* We  = (const float*)d_in[4];
    const float* be_ = (const float*)d_in[5];
    const float* ge  = (const float*)d_in[6];
    const float* bee = (const float*)d_in[7];
    const float* Wm  = (const float*)d_in[8];
    const float* bm  = (const float*)d_in[9];
    const float* gm  = (const float*)d_in[10];
    const float* bem = (const float*)d_in[11];
    const float* Ws  = (const float*)d_in[12];
    const float* bs  = (const float*)d_in[13];
    const float* gs  = (const float*)d_in[14];
    const float* bes = (const float*)d_in[15];
    const float* gn  = (const float*)d_in[16];
    const float* ben = (const float*)d_in[17];

    float* st  = (float*)d_ws;
    float* agg = (float*)d_out;           // accumulate agg directly in d_out
    __hip_bfloat16* xbuf = (__hip_bfloat16*)((char*)d_ws + 4096);
    __hip_bfloat16* ybuf = (__hip_bfloat16*)((char*)d_ws + 4096 + (size_t)NE * 64 * 2);
    const bool use_x = ws_size >= 4096 + (size_t)NE * 64 * 2;
    const bool use_y = ws_size >= 4096 + (size_t)NE * 64 * 2 + (size_t)NE * 128 * 2;

    hipMemsetAsync(d_ws, 0, 4096, stream);
    hipMemsetAsync(d_out, 0, (size_t)NN * 64 * 4, stream);

    // Phase 1: edge pre-activations + stats
    if (use_x) k_xe<true ><<<NE / 64, 256, 0, stream>>>(ef, We, be_, st, xbuf);
    else       k_xe<false><<<NE / 64, 256, 0, stream>>>(ef, We, be_, st, nullptr);
    k_fin<<<1, 64, 0, stream>>>(st + 0, st + 64, ge, bee, 1.0f / NE, st + 512, st + 576);

    // Phase 2: gated-GEMM pre-activations + stats
    if (use_x) {
        if (use_y) k_y<true, 0, true ><<<NE / 32, 256, 0, stream>>>(nf, ef, src, dst, We, be_, Wm, bm, Ws, bs, st, xbuf, ybuf, agg);
        else       k_y<true, 0, false><<<NE / 32, 256, 0, stream>>>(nf, ef, src, dst, We, be_, Wm, bm, Ws, bs, st, xbuf, ybuf, agg);
    } else       k_y<false, 0, false><<<NE / 32, 256, 0, stream>>>(nf, ef, src, dst, We, be_, Wm, bm, Ws, bs, st, xbuf, ybuf, agg);
    k_fin<<<1, 64, 0, stream>>>(st + 128, st + 192, gm, bem, 1.0f / NE, st + 640, st + 704);
    k_fin<<<1, 64, 0, stream>>>(st + 256, st + 320, gs, bes, 1.0f / NE, st + 768, st + 832);

    // Phase 3: messages + scatter-sum into agg (= d_out)
    if (use_y)      k_msg_load<<<8192, 256, 0, stream>>>(ybuf, dst, st, agg);
    else if (use_x) k_y<true, 1, false><<<NE / 32, 256, 0, stream>>>(nf, ef, src, dst, We, be_, Wm, bm, Ws, bs, st, xbuf, ybuf, agg);
    else            k_y<false, 1, false><<<NE / 32, 256, 0, stream>>>(nf, ef, src, dst, We, be_, Wm, bm, Ws, bs, st, xbuf, ybuf, agg);

    // Phase 4: node-BN stats over agg
    k_aggstats<<<1024, 256, 0, stream>>>(agg, st);
    k_fin<<<1, 64, 0, stream>>>(st + 384, st + 448, gn, ben, 1.0f / NN, st + 896, st + 960);

    // Phase 5: finalize output in place
    k_out<<<NN * 64 / 256, 256, 0, stream>>>(agg, nf, st);
}

// Round 2
// 1175.257 us; speedup vs baseline: 1.2353x; 1.2353x over previous
//
#include <hip/hip_runtime.h>

#define NN 50000
#define NE 800000
#define EPS 1e-5f

typedef __attribute__((ext_vector_type(8))) short s16x8;
typedef __attribute__((ext_vector_type(4))) short s16x4;
typedef __attribute__((ext_vector_type(4))) float f32x4;

// ws layout (bytes):
//   0      : stats block, 2048 floats (8 KB)
//   8192   : BT  bf16 [128][192]  (49152 B)   = [W_m|W_s]^T
//   57344  : BTe bf16 [64][64]    (8192 B)    = W_e^T
//   65536  : xbuf bf16 [E][64]    (102.4 MB)
// st float offsets:
//   0 S_e[64], 64 Q_e[64], 128 S_y[128], 256 Q_y[128], 384 S_n[64], 448 Q_n[64]
//   512 A_e[64], 576 C_e[64], 640 A_y[128], 768 C_y[128], 896 A_n[64], 960 C_n[64]
//   1024 biasY[128] (= bm | bs)
// agg accumulates directly in d_out (N*64 floats), finalized in place.

__device__ __forceinline__ short f2bf(float f) {
    unsigned u = __builtin_bit_cast(unsigned, f);
    unsigned r = (u + 0x7FFFu + ((u >> 16) & 1u)) >> 16;
    return (short)r;
}
__device__ __forceinline__ float bf2f(short s) {
    unsigned u = ((unsigned)(unsigned short)s) << 16;
    return __builtin_bit_cast(float, u);
}
__device__ __forceinline__ float silu_f(float x) { return x / (1.0f + __expf(-x)); }
__device__ __forceinline__ float softplus_f(float x) {
    return fmaxf(x, 0.0f) + log1pf(__expf(-fabsf(x)));
}

// ------------- prep: transpose weights to bf16, build combined bias ----------
__global__ void k_prep(const float* __restrict__ Wm, const float* __restrict__ Ws,
                       const float* __restrict__ We, const float* __restrict__ bm,
                       const float* __restrict__ bs, short* __restrict__ BT,
                       short* __restrict__ BTe, float* __restrict__ st)
{
    int i = blockIdx.x * 256 + threadIdx.x;
    if (i < 24576) {                       // BT[n][k] = (n<64?Wm:Ws)[k][n&63]
        int n = i / 192, k = i % 192;
        float w = (n < 64) ? Wm[k * 64 + n] : Ws[k * 64 + (n - 64)];
        BT[n * 192 + k] = f2bf(w);
    } else if (i < 28672) {                // BTe[n][k] = We[k][n]
        int j = i - 24576;
        int n = j >> 6, k = j & 63;
        BTe[n * 64 + k] = f2bf(We[k * 64 + n]);
    } else if (i < 28800) {                // biasY
        int j = i - 28672;
        st[1024 + j] = (j < 64) ? bm[j] : bs[j - 64];
    }
}

// ------------- BN finalize: A = g*rsqrt(var+eps), C = beta - mean*A ----------
__global__ void k_fin(const float* __restrict__ S, const float* __restrict__ Q,
                      const float* __restrict__ g, const float* __restrict__ b,
                      float inv_cnt, float* __restrict__ A, float* __restrict__ C)
{
    int j = threadIdx.x;
    float m = S[j] * inv_cnt;
    float v = Q[j] * inv_cnt - m * m;
    float a = g[j] * rsqrtf(v + EPS);
    A[j] = a;
    C[j] = b[j] - m * a;
}

// ------------- Phase 1: x = ef @ W_e + b_e (MFMA bf16); stats; store xbuf ----
__global__ __launch_bounds__(256, 2) void k_xe_m(
    const float* __restrict__ ef, const short* __restrict__ BTe,
    const float* __restrict__ be_, float* __restrict__ st,
    short* __restrict__ xbuf)
{
    __shared__ short sA[128][72];
    __shared__ short sB[64][72];
    __shared__ float sSQ[128];
    __shared__ float sBe[64];
    const int tx = threadIdx.x;
    const long e0 = (long)blockIdx.x * 128;

    if (tx < 128) sSQ[tx] = 0.f;
    if (tx < 64) sBe[tx] = be_[tx];
    #pragma unroll
    for (int i = tx; i < 512; i += 256) {            // stage W_e^T
        int n = i >> 3, c = (i & 7) * 8;
        *(s16x8*)&sB[n][c] = ((const s16x8*)BTe)[i];
    }
    {                                                 // stage A (fp32->bf16)
        const int e = tx >> 1, half = tx & 1;
        const float* p = ef + (e0 + e) * 64 + 32 * half;
        #pragma unroll
        for (int c = 0; c < 32; c += 4) {
            float4 v = *(const float4*)(p + c);
            s16x4 w; w.x = f2bf(v.x); w.y = f2bf(v.y); w.z = f2bf(v.z); w.w = f2bf(v.w);
            *(s16x4*)&sA[e][32 * half + c] = w;
        }
    }
    __syncthreads();

    const int w = tx >> 6, lane = tx & 63, lr = lane & 15, lg = lane >> 4;
    f32x4 acc[2][4];
    for (int m = 0; m < 2; ++m) for (int n = 0; n < 4; ++n)
        for (int q = 0; q < 4; ++q) acc[m][n][q] = 0.f;

    #pragma unroll
    for (int ks = 0; ks < 2; ++ks) {
        s16x8 a[2], b[4];
        #pragma unroll
        for (int m = 0; m < 2; ++m) a[m] = *(const s16x8*)&sA[32 * w + 16 * m + lr][ks * 32 + 8 * lg];
        #pragma unroll
        for (int n = 0; n < 4; ++n) b[n] = *(const s16x8*)&sB[16 * n + lr][ks * 32 + 8 * lg];
        #pragma unroll
        for (int m = 0; m < 2; ++m)
            #pragma unroll
            for (int n = 0; n < 4; ++n)
                acc[m][n] = __builtin_amdgcn_mfma_f32_16x16x32_bf16(a[m], b[n], acc[m][n], 0, 0, 0);
    }

    #pragma unroll
    for (int n = 0; n < 4; ++n) {                    // bias + stats
        int col = 16 * n + lr;
        float b = sBe[col];
        float s = 0.f, q = 0.f;
        #pragma unroll
        for (int m = 0; m < 2; ++m)
            #pragma unroll
            for (int r = 0; r < 4; ++r) { float y = acc[m][n][r] + b; s += y; q += y * y; }
        s += __shfl_xor(s, 16); s += __shfl_xor(s, 32);
        q += __shfl_xor(q, 16); q += __shfl_xor(q, 32);
        if (lg == 0) { atomicAdd(&sSQ[col], s); atomicAdd(&sSQ[64 + col], q); }
    }
    __syncthreads();
    short* sX = &sA[0][0];                            // overlay [128][64]
    #pragma unroll
    for (int n = 0; n < 4; ++n) {
        int col = 16 * n + lr;
        float b = sBe[col];
        #pragma unroll
        for (int m = 0; m < 2; ++m)
            #pragma unroll
            for (int r = 0; r < 4; ++r) {
                int row = 32 * w + 16 * m + 4 * lg + r;
                sX[row * 64 + col] = f2bf(acc[m][n][r] + b);
            }
    }
    __syncthreads();
    #pragma unroll
    for (int i = tx; i < 1024; i += 256)
        ((s16x8*)(xbuf + e0 * 64))[i] = ((const s16x8*)sX)[i];
    if (tx < 64) atomicAdd(&st[tx], sSQ[tx]);
    else if (tx < 128) atomicAdd(&st[64 + (tx - 64)], sSQ[tx]);
}

// ------------- Phase 2/3: y = h_combine @ [W_m|W_s] (MFMA bf16) --------------
// MODE 0: column stats of y.   MODE 1: msg = silu(bn_m)*softplus(bn_s), scatter.
template<int MODE>
__global__ __launch_bounds__(256, 1) void k_yg(
    const float* __restrict__ nf, const int* __restrict__ src,
    const int* __restrict__ dst, const short* __restrict__ xbuf,
    const short* __restrict__ BT, float* __restrict__ st,
    float* __restrict__ agg)
{
    __shared__ short sA[128][200];
    __shared__ short sB[128][200];
    __shared__ float sSQ[256];
    __shared__ float sAeCe[128];
    __shared__ float sMisc[256];     // MODE1: A_y[128], C_y[128]
    __shared__ float sBias[128];
    __shared__ int   sDst[128];

    const int tx = threadIdx.x;
    const long e0 = (long)blockIdx.x * 128;

    if (tx < 128) sAeCe[tx] = st[512 + tx];
    if (tx < 128) sBias[tx] = st[1024 + tx];
    if (MODE == 0) sSQ[tx] = 0.f;
    else {
        sMisc[tx] = st[640 + tx];
        if (tx < 128) sDst[tx] = dst[e0 + tx];
    }

    for (int i = tx; i < 3072; i += 256) {           // stage B^T
        int n = i / 24, c = (i % 24) * 8;
        *(s16x8*)&sB[n][c] = ((const s16x8*)BT)[i];
    }

    const int e = tx >> 1, half = tx & 1;
    {                                                 // gather node rows
        int sn = src[e0 + e], dn = dst[e0 + e];
        const float* ps = nf + (size_t)sn * 64 + 32 * half;
        const float* pd = nf + (size_t)dn * 64 + 32 * half;
        #pragma unroll
        for (int c = 0; c < 32; c += 4) {
            float4 v = *(const float4*)(ps + c);
            s16x4 w; w.x = f2bf(v.x); w.y = f2bf(v.y); w.z = f2bf(v.z); w.w = f2bf(v.w);
            *(s16x4*)&sA[e][32 * half + c] = w;
            float4 v2 = *(const float4*)(pd + c);
            s16x4 w2; w2.x = f2bf(v2.x); w2.y = f2bf(v2.y); w2.z = f2bf(v2.z); w2.w = f2bf(v2.w);
            *(s16x4*)&sA[e][64 + 32 * half + c] = w2;
        }
    }
    __syncthreads();                                  // sAeCe ready
    {                                                 // hm = silu(bn_e(x))
        const short* px = xbuf + (size_t)(e0 + e) * 64 + 32 * half;
        #pragma unroll
        for (int c = 0; c < 32; c += 4) {
            s16x4 xv = *(const s16x4*)(px + c);
            s16x4 hv;
            #pragma unroll
            for (int t = 0; t < 4; ++t) {
                int j = 32 * half + c + t;
                float x = bf2f(xv[t]);
                hv[t] = f2bf(silu_f(fmaf(x, sAeCe[j], sAeCe[64 + j])));
            }
            *(s16x4*)&sA[e][128 + 32 * half + c] = hv;
        }
    }
    __syncthreads();

    const int w = tx >> 6, lane = tx & 63, lr = lane & 15, lg = lane >> 4;
    const int wr = w >> 1, wc = w & 1;
    f32x4 acc[4][4];
    for (int m = 0; m < 4; ++m) for (int n = 0; n < 4; ++n)
        for (int q = 0; q < 4; ++q) acc[m][n][q] = 0.f;

    #pragma unroll
    for (int ks = 0; ks < 6; ++ks) {
        s16x8 a[4], b[4];
        #pragma unroll
        for (int m = 0; m < 4; ++m) a[m] = *(const s16x8*)&sA[64 * wr + 16 * m + lr][ks * 32 + 8 * lg];
        #pragma unroll
        for (int n = 0; n < 4; ++n) b[n] = *(const s16x8*)&sB[64 * wc + 16 * n + lr][ks * 32 + 8 * lg];
        #pragma unroll
        for (int m = 0; m < 4; ++m)
            #pragma unroll
            for (int n = 0; n < 4; ++n)
                acc[m][n] = __builtin_amdgcn_mfma_f32_16x16x32_bf16(a[m], b[n], acc[m][n], 0, 0, 0);
    }

    if (MODE == 0) {
        #pragma unroll
        for (int n = 0; n < 4; ++n) {
            int col = 64 * wc + 16 * n + lr;
            float b = sBias[col];
            float s = 0.f, q = 0.f;
            #pragma unroll
            for (int m = 0; m < 4; ++m)
                #pragma unroll
                for (int r = 0; r < 4; ++r) { float y = acc[m][n][r] + b; s += y; q += y * y; }
            s += __shfl_xor(s, 16); s += __shfl_xor(s, 32);
            q += __shfl_xor(q, 16); q += __shfl_xor(q, 32);
            if (lg == 0) { atomicAdd(&sSQ[col], s); atomicAdd(&sSQ[128 + col], q); }
        }
        __syncthreads();
        if (tx < 128) atomicAdd(&st[128 + tx], sSQ[tx]);
        else atomicAdd(&st[256 + (tx - 128)], sSQ[tx]);
    } else {
        __syncthreads();                              // all waves done with sB
        float* sG = (float*)&sB[0][0];                // overlay [128][68]
        if (wc == 1) {                                // softplus gate (cols 64..127)
            #pragma unroll
            for (int n = 0; n < 4; ++n) {
                int cs = 16 * n + lr;
                float b = sBias[64 + cs], A = sMisc[64 + cs], C = sMisc[192 + cs];
                #pragma unroll
                for (int m = 0; m < 4; ++m)
                    #pragma unroll
                    for (int r = 0; r < 4; ++r) {
                        int row = 64 * wr + 16 * m + 4 * lg + r;
                        float y = acc[m][n][r] + b;
                        sG[row * 68 + cs] = softplus_f(fmaf(y, A, C));
                    }
            }
        }
        __syncthreads();
        if (wc == 0) {                                // silu * gate, scatter
            #pragma unroll
            for (int n = 0; n < 4; ++n) {
                int col = 16 * n + lr;
                float b = sBias[col], A = sMisc[col], C = sMisc[128 + col];
                #pragma unroll
                for (int m = 0; m < 4; ++m)
                    #pragma unroll
                    for (int r = 0; r < 4; ++r) {
                        int row = 64 * wr + 16 * m + 4 * lg + r;
                        float y = acc[m][n][r] + b;
                        float msg = silu_f(fmaf(y, A, C)) * sG[row * 68 + col];
                        atomicAdd(&agg[(size_t)sDst[row] * 64 + col], msg);
                    }
            }
        }
    }
}

// ------------- Phase 4: agg column stats -------------------------------------
__global__ __launch_bounds__(256) void k_aggstats(const float* __restrict__ agg,
                                                  float* __restrict__ st)
{
    __shared__ float red[2][4][64];
    float ls = 0.f, lq = 0.f;
    const long total = (long)NN * 64;
    for (long t = (long)blockIdx.x * 256 + threadIdx.x; t < total;
         t += (long)gridDim.x * 256) {
        float a = agg[t];
        ls += a; lq += a * a;
    }
    int j = threadIdx.x & 63, g = threadIdx.x >> 6;
    red[0][g][j] = ls; red[1][g][j] = lq;
    __syncthreads();
    if (threadIdx.x < 64) {
        float s = red[0][0][j] + red[0][1][j] + red[0][2][j] + red[0][3][j];
        atomicAdd(&st[384 + j], s);
    } else if (threadIdx.x < 128) {
        int jj = threadIdx.x - 64;
        float q = red[1][0][jj] + red[1][1][jj] + red[1][2][jj] + red[1][3][jj];
        atomicAdd(&st[448 + jj], q);
    }
}

// ------------- Phase 5: out = softplus(bn_n(agg) + nf), in place -------------
__global__ __launch_bounds__(256) void k_out(float* __restrict__ outagg,
                                             const float* __restrict__ nf,
                                             const float* __restrict__ st)
{
    long t = (long)blockIdx.x * 256 + threadIdx.x;
    int j = (int)(t & 63);
    float a = outagg[t];
    outagg[t] = softplus_f(fmaf(a, st[896 + j], st[960 + j]) + nf[t]);
}

extern "C" void kernel_launch(void* const* d_in, const int* in_sizes, int n_in,
                              void* d_out, int out_size, void* d_ws, size_t ws_size,
                              hipStream_t stream)
{
    (void)in_sizes; (void)n_in; (void)out_size; (void)ws_size;
    const float* nf  = (const float*)d_in[0];
    const float* ef  = (const float*)d_in[1];
    const int*   src = (const int*)d_in[2];
    const int*   dst = (const int*)d_in[3];
    const float* We  = (const float*)d_in[4];
    const float* be_ = (const float*)d_in[5];
    const float* ge  = (const float*)d_in[6];
    const float* bee = (const float*)d_in[7];
    const float* Wm  = (const float*)d_in[8];
    const float* bm  = (const float*)d_in[9];
    const float* gm  = (const float*)d_in[10];
    const float* bem = (const float*)d_in[11];
    const float* Ws  = (const float*)d_in[12];
    const float* bs  = (const float*)d_in[13];
    const float* gs  = (const float*)d_in[14];
    const float* bes = (const float*)d_in[15];
    const float* gn  = (const float*)d_in[16];
    const float* ben = (const float*)d_in[17];

    float* st   = (float*)d_ws;
    short* BT   = (short*)((char*)d_ws + 8192);
    short* BTe  = (short*)((char*)d_ws + 57344);
    short* xbuf = (short*)((char*)d_ws + 65536);
    float* agg  = (float*)d_out;

    hipMemsetAsync(d_ws, 0, 8192, stream);
    hipMemsetAsync(d_out, 0, (size_t)NN * 64 * 4, stream);

    k_prep<<<113, 256, 0, stream>>>(Wm, Ws, We, bm, bs, BT, BTe, st);

    k_xe_m<<<NE / 128, 256, 0, stream>>>(ef, BTe, be_, st, xbuf);
    k_fin<<<1, 64, 0, stream>>>(st + 0, st + 64, ge, bee, 1.0f / NE, st + 512, st + 576);

    k_yg<0><<<NE / 128, 256, 0, stream>>>(nf, src, dst, xbuf, BT, st, agg);
    k_fin<<<1, 64, 0, stream>>>(st + 128, st + 256, gm, bem, 1.0f / NE, st + 640, st + 768);
    k_fin<<<1, 64, 0, stream>>>(st + 192, st + 320, gs, bes, 1.0f / NE, st + 704, st + 832);

    k_yg<1><<<NE / 128, 256, 0, stream>>>(nf, src, dst, xbuf, BT, st, agg);

    k_aggstats<<<1024, 256, 0, stream>>>(agg, st);
    k_fin<<<1, 64, 0, stream>>>(st + 384, st + 448, gn, ben, 1.0f / NN, st + 896, st + 960);

    k_out<<<NN * 64 / 256, 256, 0, stream>>>(agg, nf, st);
}

// Round 3
// 754.891 us; speedup vs baseline: 1.9232x; 1.5569x over previous
//
#include <hip/hip_runtime.h>

#define NN 50000
#define NE 800000
#define EPS 1e-5f

typedef __attribute__((ext_vector_type(8))) short s16x8;
typedef __attribute__((ext_vector_type(4))) short s16x4;
typedef __attribute__((ext_vector_type(4))) float f32x4;

// ws layout (bytes):
//   0      : stats block, 2048 floats (8 KB)
//   8192   : BT  bf16 [128][192]  (49152 B)   = [W_m|W_s]^T
//   57344  : BTe bf16 [64][64]    (8192 B)    = W_e^T
//   65536  : xbuf bf16 [E][64]    (102.4 MB)
// st float offsets:
//   0 S_e[64], 64 Q_e[64], 128 S_y[128], 256 Q_y[128], 384 S_n[64], 448 Q_n[64]
//   512 A_e[64], 576 C_e[64], 640 A_y[128], 768 C_y[128], 896 A_n[64], 960 C_n[64]
//   1024 biasY[128] (= bm | bs)
// agg accumulates directly in d_out (N*64 floats), finalized in place.

__device__ __forceinline__ short f2bf(float f) {
    unsigned u = __builtin_bit_cast(unsigned, f);
    unsigned r = (u + 0x7FFFu + ((u >> 16) & 1u)) >> 16;
    return (short)r;
}
__device__ __forceinline__ float bf2f(short s) {
    unsigned u = ((unsigned)(unsigned short)s) << 16;
    return __builtin_bit_cast(float, u);
}
__device__ __forceinline__ float silu_f(float x) { return x / (1.0f + __expf(-x)); }
__device__ __forceinline__ float softplus_f(float x) {
    return fmaxf(x, 0.0f) + log1pf(__expf(-fabsf(x)));
}
// XOR swizzle for a row-major [128][192]-short LDS tile (row stride 384 B =
// 3 aligned 128 B blocks): flip the 16 B-slot index inside each 128 B block
// by row&7. Fragment reads (col fixed, row varies per lane) then spread
// across all 8 bank groups -> 2-way max (free).
__device__ __forceinline__ int swz(int row, int col) {
    return row * 192 + (col ^ ((row & 7) << 3));
}

// ------------- prep: transpose weights to bf16, build combined bias ----------
__global__ void k_prep(const float* __restrict__ Wm, const float* __restrict__ Ws,
                       const float* __restrict__ We, const float* __restrict__ bm,
                       const float* __restrict__ bs, short* __restrict__ BT,
                       short* __restrict__ BTe, float* __restrict__ st)
{
    int i = blockIdx.x * 256 + threadIdx.x;
    if (i < 24576) {                       // BT[n][k] = (n<64?Wm:Ws)[k][n&63]
        int n = i / 192, k = i % 192;
        float w = (n < 64) ? Wm[k * 64 + n] : Ws[k * 64 + (n - 64)];
        BT[n * 192 + k] = f2bf(w);
    } else if (i < 28672) {                // BTe[n][k] = We[k][n]
        int j = i - 24576;
        int n = j >> 6, k = j & 63;
        BTe[n * 64 + k] = f2bf(We[k * 64 + n]);
    } else if (i < 28800) {                // biasY
        int j = i - 28672;
        st[1024 + j] = (j < 64) ? bm[j] : bs[j - 64];
    }
}

// ------------- BN finalize: A = g*rsqrt(var+eps), C = beta - mean*A ----------
__global__ void k_fin(const float* __restrict__ S, const float* __restrict__ Q,
                      const float* __restrict__ g, const float* __restrict__ b,
                      float inv_cnt, float* __restrict__ A, float* __restrict__ C)
{
    int j = threadIdx.x;
    float m = S[j] * inv_cnt;
    float v = Q[j] * inv_cnt - m * m;
    float a = g[j] * rsqrtf(v + EPS);
    A[j] = a;
    C[j] = b[j] - m * a;
}

// ------------- Phase 1: x = ef @ W_e + b_e (MFMA bf16); stats; store xbuf ----
__global__ __launch_bounds__(256, 4) void k_xe_m(
    const float* __restrict__ ef, const short* __restrict__ BTe,
    const float* __restrict__ be_, float* __restrict__ st,
    short* __restrict__ xbuf)
{
    __shared__ short sA[128][72];
    __shared__ short sB[64][72];
    __shared__ float sSQ[128];
    __shared__ float sBe[64];
    const int tx = threadIdx.x;
    const long e0 = (long)blockIdx.x * 128;

    if (tx < 128) sSQ[tx] = 0.f;
    if (tx < 64) sBe[tx] = be_[tx];
    #pragma unroll
    for (int i = tx; i < 512; i += 256) {            // stage W_e^T
        int n = i >> 3, c = (i & 7) * 8;
        *(s16x8*)&sB[n][c] = ((const s16x8*)BTe)[i];
    }
    {                                                 // stage A (fp32->bf16)
        const int e = tx >> 1, half = tx & 1;
        const float* p = ef + (e0 + e) * 64 + 32 * half;
        #pragma unroll
        for (int c = 0; c < 32; c += 4) {
            float4 v = *(const float4*)(p + c);
            s16x4 w; w.x = f2bf(v.x); w.y = f2bf(v.y); w.z = f2bf(v.z); w.w = f2bf(v.w);
            *(s16x4*)&sA[e][32 * half + c] = w;
        }
    }
    __syncthreads();

    const int w = tx >> 6, lane = tx & 63, lr = lane & 15, lg = lane >> 4;
    f32x4 acc[2][4];
    for (int m = 0; m < 2; ++m) for (int n = 0; n < 4; ++n)
        for (int q = 0; q < 4; ++q) acc[m][n][q] = 0.f;

    #pragma unroll
    for (int ks = 0; ks < 2; ++ks) {
        s16x8 a[2], b[4];
        #pragma unroll
        for (int m = 0; m < 2; ++m) a[m] = *(const s16x8*)&sA[32 * w + 16 * m + lr][ks * 32 + 8 * lg];
        #pragma unroll
        for (int n = 0; n < 4; ++n) b[n] = *(const s16x8*)&sB[16 * n + lr][ks * 32 + 8 * lg];
        #pragma unroll
        for (int m = 0; m < 2; ++m)
            #pragma unroll
            for (int n = 0; n < 4; ++n)
                acc[m][n] = __builtin_amdgcn_mfma_f32_16x16x32_bf16(a[m], b[n], acc[m][n], 0, 0, 0);
    }

    #pragma unroll
    for (int n = 0; n < 4; ++n) {                    // bias + stats
        int col = 16 * n + lr;
        float b = sBe[col];
        float s = 0.f, q = 0.f;
        #pragma unroll
        for (int m = 0; m < 2; ++m)
            #pragma unroll
            for (int r = 0; r < 4; ++r) { float y = acc[m][n][r] + b; s += y; q += y * y; }
        s += __shfl_xor(s, 16); s += __shfl_xor(s, 32);
        q += __shfl_xor(q, 16); q += __shfl_xor(q, 32);
        if (lg == 0) { atomicAdd(&sSQ[col], s); atomicAdd(&sSQ[64 + col], q); }
    }
    __syncthreads();
    short* sX = &sA[0][0];                            // overlay [128][64]
    #pragma unroll
    for (int n = 0; n < 4; ++n) {
        int col = 16 * n + lr;
        float b = sBe[col];
        #pragma unroll
        for (int m = 0; m < 2; ++m)
            #pragma unroll
            for (int r = 0; r < 4; ++r) {
                int row = 32 * w + 16 * m + 4 * lg + r;
                sX[row * 64 + col] = f2bf(acc[m][n][r] + b);
            }
    }
    __syncthreads();
    #pragma unroll
    for (int i = tx; i < 1024; i += 256)
        ((s16x8*)(xbuf + e0 * 64))[i] = ((const s16x8*)sX)[i];
    if (tx < 64) atomicAdd(&st[tx], sSQ[tx]);
    else if (tx < 128) atomicAdd(&st[64 + (tx - 64)], sSQ[tx]);
}

// ------------- Phase 2/3 shared body: y = h_combine @ [W_m|W_s] (MFMA) -------
// MODE 0: column stats of y.   MODE 1: msg = silu(bn_m)*softplus(bn_s), scatter.
// sA swizzled [128][192]; B fragments read straight from global BT (48 KB,
// L2-resident broadcast across all blocks). 3 blocks/CU.
template<int MODE>
__device__ __forceinline__ void y_body(
    const float* __restrict__ nf, const int* __restrict__ src,
    const int* __restrict__ dst, const short* __restrict__ xbuf,
    const short* __restrict__ BT, float* __restrict__ st,
    float* __restrict__ agg)
{
    __shared__ short sA[128 * 192];
    __shared__ float sSQ[MODE == 0 ? 256 : 1];
    __shared__ float sAeCe[128];
    __shared__ float sMisc[MODE == 1 ? 256 : 1];
    __shared__ float sBias[128];
    __shared__ int   sDst[MODE == 1 ? 128 : 1];

    const int tx = threadIdx.x;
    const long e0 = (long)blockIdx.x * 128;

    if (tx < 128) sAeCe[tx] = st[512 + tx];
    if (tx < 128) sBias[tx] = st[1024 + tx];
    if (MODE == 0) sSQ[tx] = 0.f;
    else {
        sMisc[tx] = st[640 + tx];
        if (tx < 128) sDst[tx] = dst[e0 + tx];
    }

    const int e = tx >> 1, half = tx & 1;
    {                                                 // gather node rows
        int sn = src[e0 + e], dn = dst[e0 + e];
        const float* ps = nf + (size_t)sn * 64 + 32 * half;
        const float* pd = nf + (size_t)dn * 64 + 32 * half;
        #pragma unroll
        for (int c = 0; c < 32; c += 4) {
            float4 v = *(const float4*)(ps + c);
            s16x4 w; w.x = f2bf(v.x); w.y = f2bf(v.y); w.z = f2bf(v.z); w.w = f2bf(v.w);
            *(s16x4*)&sA[swz(e, 32 * half + c)] = w;
            float4 v2 = *(const float4*)(pd + c);
            s16x4 w2; w2.x = f2bf(v2.x); w2.y = f2bf(v2.y); w2.z = f2bf(v2.z); w2.w = f2bf(v2.w);
            *(s16x4*)&sA[swz(e, 64 + 32 * half + c)] = w2;
        }
    }
    __syncthreads();                                  // sAeCe ready
    {                                                 // hm = silu(bn_e(x))
        const short* px = xbuf + (size_t)(e0 + e) * 64 + 32 * half;
        #pragma unroll
        for (int c = 0; c < 32; c += 4) {
            s16x4 xv = *(const s16x4*)(px + c);
            s16x4 hv;
            #pragma unroll
            for (int t = 0; t < 4; ++t) {
                int j = 32 * half + c + t;
                float x = bf2f(xv[t]);
                hv[t] = f2bf(silu_f(fmaf(x, sAeCe[j], sAeCe[64 + j])));
            }
            *(s16x4*)&sA[swz(e, 128 + 32 * half + c)] = hv;
        }
    }
    __syncthreads();

    const int w = tx >> 6, lane = tx & 63, lr = lane & 15, lg = lane >> 4;
    const int wr = w >> 1, wc = w & 1;
    f32x4 acc[4][4];
    for (int m = 0; m < 4; ++m) for (int n = 0; n < 4; ++n)
        for (int q = 0; q < 4; ++q) acc[m][n][q] = 0.f;

    const s16x8* Bg = (const s16x8*)BT;               // [128 rows][24 frags]
    const int brow = (64 * wc + lr) * 24 + lg;

    #pragma unroll
    for (int ks = 0; ks < 6; ++ks) {
        s16x8 a[4], b[4];
        #pragma unroll
        for (int m = 0; m < 4; ++m)
            a[m] = *(const s16x8*)&sA[swz(64 * wr + 16 * m + lr, ks * 32 + 8 * lg)];
        #pragma unroll
        for (int n = 0; n < 4; ++n)
            b[n] = Bg[brow + 384 * n + 4 * ks];
        #pragma unroll
        for (int m = 0; m < 4; ++m)
            #pragma unroll
            for (int n = 0; n < 4; ++n)
                acc[m][n] = __builtin_amdgcn_mfma_f32_16x16x32_bf16(a[m], b[n], acc[m][n], 0, 0, 0);
    }

    if (MODE == 0) {
        #pragma unroll
        for (int n = 0; n < 4; ++n) {
            int col = 64 * wc + 16 * n + lr;
            float b = sBias[col];
            float s = 0.f, q = 0.f;
            #pragma unroll
            for (int m = 0; m < 4; ++m)
                #pragma unroll
                for (int r = 0; r < 4; ++r) { float y = acc[m][n][r] + b; s += y; q += y * y; }
            s += __shfl_xor(s, 16); s += __shfl_xor(s, 32);
            q += __shfl_xor(q, 16); q += __shfl_xor(q, 32);
            if (lg == 0) { atomicAdd(&sSQ[col], s); atomicAdd(&sSQ[128 + col], q); }
        }
        __syncthreads();
        if (tx < 128) atomicAdd(&st[128 + tx], sSQ[tx]);
        else atomicAdd(&st[256 + (tx - 128)], sSQ[tx]);
    } else {
        __syncthreads();                              // all waves done with sA
        float* sG = (float*)&sA[0];                   // overlay [128][68] floats
        if (wc == 1) {                                // softplus gate (cols 64..127)
            #pragma unroll
            for (int n = 0; n < 4; ++n) {
                int cs = 16 * n + lr;
                float b = sBias[64 + cs], A = sMisc[64 + cs], C = sMisc[192 + cs];
                #pragma unroll
                for (int m = 0; m < 4; ++m)
                    #pragma unroll
                    for (int r = 0; r < 4; ++r) {
                        int row = 64 * wr + 16 * m + 4 * lg + r;
                        float y = acc[m][n][r] + b;
                        sG[row * 68 + cs] = softplus_f(fmaf(y, A, C));
                    }
            }
        }
        __syncthreads();
        if (wc == 0) {                                // silu * gate, scatter
            #pragma unroll
            for (int n = 0; n < 4; ++n) {
                int col = 16 * n + lr;
                float b = sBias[col], A = sMisc[col], C = sMisc[128 + col];
                #pragma unroll
                for (int m = 0; m < 4; ++m)
                    #pragma unroll
                    for (int r = 0; r < 4; ++r) {
                        int row = 64 * wr + 16 * m + 4 * lg + r;
                        float y = acc[m][n][r] + b;
                        float msg = silu_f(fmaf(y, A, C)) * sG[row * 68 + col];
                        atomicAdd(&agg[(size_t)sDst[row] * 64 + col], msg);
                    }
            }
        }
    }
}

__global__ __launch_bounds__(256, 3) void k_y_stats(
    const float* __restrict__ nf, const int* __restrict__ src,
    const int* __restrict__ dst, const short* __restrict__ xbuf,
    const short* __restrict__ BT, float* __restrict__ st,
    float* __restrict__ agg)
{
    y_body<0>(nf, src, dst, xbuf, BT, st, agg);
}

__global__ __launch_bounds__(256, 3) void k_y_msg(
    const float* __restrict__ nf, const int* __restrict__ src,
    const int* __restrict__ dst, const short* __restrict__ xbuf,
    const short* __restrict__ BT, float* __restrict__ st,
    float* __restrict__ agg)
{
    y_body<1>(nf, src, dst, xbuf, BT, st, agg);
}

// ------------- Phase 4: agg column stats -------------------------------------
__global__ __launch_bounds__(256) void k_aggstats(const float* __restrict__ agg,
                                                  float* __restrict__ st)
{
    __shared__ float red[2][4][64];
    float ls = 0.f, lq = 0.f;
    const long total = (long)NN * 64;
    for (long t = (long)blockIdx.x * 256 + threadIdx.x; t < total;
         t += (long)gridDim.x * 256) {
        float a = agg[t];
        ls += a; lq += a * a;
    }
    int j = threadIdx.x & 63, g = threadIdx.x >> 6;
    red[0][g][j] = ls; red[1][g][j] = lq;
    __syncthreads();
    if (threadIdx.x < 64) {
        float s = red[0][0][j] + red[0][1][j] + red[0][2][j] + red[0][3][j];
        atomicAdd(&st[384 + j], s);
    } else if (threadIdx.x < 128) {
        int jj = threadIdx.x - 64;
        float q = red[1][0][jj] + red[1][1][jj] + red[1][2][jj] + red[1][3][jj];
        atomicAdd(&st[448 + jj], q);
    }
}

// ------------- Phase 5: out = softplus(bn_n(agg) + nf), in place -------------
__global__ __launch_bounds__(256) void k_out(float* __restrict__ outagg,
                                             const float* __restrict__ nf,
                                             const float* __restrict__ st)
{
    long t = (long)blockIdx.x * 256 + threadIdx.x;
    int j = (int)(t & 63);
    float a = outagg[t];
    outagg[t] = softplus_f(fmaf(a, st[896 + j], st[960 + j]) + nf[t]);
}

extern "C" void kernel_launch(void* const* d_in, const int* in_sizes, int n_in,
                              void* d_out, int out_size, void* d_ws, size_t ws_size,
                              hipStream_t stream)
{
    (void)in_sizes; (void)n_in; (void)out_size; (void)ws_size;
    const float* nf  = (const float*)d_in[0];
    const float* ef  = (const float*)d_in[1];
    const int*   src = (const int*)d_in[2];
    const int*   dst = (const int*)d_in[3];
    const float* We  = (const float*)d_in[4];
    const float* be_ = (const float*)d_in[5];
    const float* ge  = (const float*)d_in[6];
    const float* bee = (const float*)d_in[7];
    const float* Wm  = (const float*)d_in[8];
    const float* bm  = (const float*)d_in[9];
    const float* gm  = (const float*)d_in[10];
    const float* bem = (const float*)d_in[11];
    const float* Ws  = (const float*)d_in[12];
    const float* bs  = (const float*)d_in[13];
    const float* gs  = (const float*)d_in[14];
    const float* bes = (const float*)d_in[15];
    const float* gn  = (const float*)d_in[16];
    const float* ben = (const float*)d_in[17];

    float* st   = (float*)d_ws;
    short* BT   = (short*)((char*)d_ws + 8192);
    short* BTe  = (short*)((char*)d_ws + 57344);
    short* xbuf = (short*)((char*)d_ws + 65536);
    float* agg  = (float*)d_out;

    hipMemsetAsync(d_ws, 0, 8192, stream);
    hipMemsetAsync(d_out, 0, (size_t)NN * 64 * 4, stream);

    k_prep<<<113, 256, 0, stream>>>(Wm, Ws, We, bm, bs, BT, BTe, st);

    k_xe_m<<<NE / 128, 256, 0, stream>>>(ef, BTe, be_, st, xbuf);
    k_fin<<<1, 64, 0, stream>>>(st + 0, st + 64, ge, bee, 1.0f / NE, st + 512, st + 576);

    k_y_stats<<<NE / 128, 256, 0, stream>>>(nf, src, dst, xbuf, BT, st, agg);
    k_fin<<<1, 64, 0, stream>>>(st + 128, st + 256, gm, bem, 1.0f / NE, st + 640, st + 768);
    k_fin<<<1, 64, 0, stream>>>(st + 192, st + 320, gs, bes, 1.0f / NE, st + 704, st + 832);

    k_y_msg<<<NE / 128, 256, 0, stream>>>(nf, src, dst, xbuf, BT, st, agg);

    k_aggstats<<<1024, 256, 0, stream>>>(agg, st);
    k_fin<<<1, 64, 0, stream>>>(st + 384, st + 448, gn, ben, 1.0f / NN, st + 896, st + 960);

    k_out<<<NN * 64 / 256, 256, 0, stream>>>(agg, nf, st);
}